// Round 10
// baseline (253.727 us; speedup 1.0000x reference)
//
#include <hip/hip_runtime.h>

#define SQ   2048
#define HD   128
#define NH   16
#define HDIM 2048

typedef short bf16x8 __attribute__((ext_vector_type(8)));
typedef float f32x4  __attribute__((ext_vector_type(4)));

#if __has_builtin(__builtin_amdgcn_exp2f)
#define EXP2(x) __builtin_amdgcn_exp2f(x)
#else
#define EXP2(x) exp2f(x)
#endif

__device__ __forceinline__ unsigned short f2bf(float x) {
    union { float f; unsigned u; } v; v.f = x;
    unsigned r = v.u + 0x7fffu + ((v.u >> 16) & 1u);   // RNE
    return (unsigned short)(r >> 16);
}

__device__ __forceinline__ void gl_lds16(const void* g, void* l) {
    __builtin_amdgcn_global_load_lds(
        (const __attribute__((address_space(1))) unsigned*)g,
        (__attribute__((address_space(3))) unsigned*)l, 16, 0, 0);
}

// ---------------------------------------------------------------------------
// Swizzled tile staging (256-thread blocks): ROWS x 128 bf16, row stride
// 256 B, 16B-chunk index XORed with (row&7); swizzle via per-lane GLOBAL src.
// ---------------------------------------------------------------------------
template<int ROWS>
__device__ __forceinline__ void stage_tile(const unsigned short* __restrict__ src,
                                           long ld, unsigned short* dst)
{
    const int tid = threadIdx.x;
    #pragma unroll
    for (int c = 0; c < ROWS / 16; ++c) {
        int o   = c * 4096 + tid * 16;
        int row = o >> 8;
        int pch = (o >> 4) & 15;
        int lch = pch ^ (row & 7);
        gl_lds16(src + (long)row * ld + lch * 8, (char*)dst + o);
    }
}

// 512-thread variant (k_attn)
template<int ROWS>
__device__ __forceinline__ void stage512(const unsigned short* __restrict__ src,
                                         long ld, unsigned short* dst)
{
    const int tid = threadIdx.x;
    #pragma unroll
    for (int c = 0; c < ROWS / 32; ++c) {
        int o   = c * 8192 + tid * 16;
        int row = o >> 8;
        int pch = (o >> 4) & 15;
        int lch = pch ^ (row & 7);
        gl_lds16(src + (long)row * ld + lch * 8, (char*)dst + o);
    }
}

__device__ __forceinline__ bf16x8 frag_ld(const unsigned short* buf, int row, int chunk)
{
    int o = row * 256 + ((chunk ^ (row & 7)) << 4);
    return *(const bf16x8*)((const char*)buf + o);
}

__device__ __forceinline__ void p_st(unsigned short* buf, int row, int col, unsigned short v)
{
    int o = row * 256 + ((((col >> 3) ^ (row & 7))) << 4) + ((col & 7) << 1);
    *(unsigned short*)((char*)buf + o) = v;
}

// ---------------------------------------------------------------------------
// f32 -> bf16, 6 tensors in one launch (blockIdx.z selects tensor)
// ---------------------------------------------------------------------------
struct CvtPtrs {
    const float* s[6];
    unsigned short* d[6];
};

__global__ __launch_bounds__(256)
void k_cvt6(CvtPtrs p, long n)
{
    const float* __restrict__ s = p.s[blockIdx.z];
    unsigned short* __restrict__ d = p.d[blockIdx.z];
    long i = ((long)blockIdx.x * 256 + threadIdx.x) * 8;
    if (i >= n) return;
    float4 a = *(const float4*)(s + i);
    float4 b = *(const float4*)(s + i + 4);
    unsigned short t[8] = { f2bf(a.x), f2bf(a.y), f2bf(a.z), f2bf(a.w),
                            f2bf(b.x), f2bf(b.y), f2bf(b.z), f2bf(b.w) };
    *(int4*)(d + i) = *(const int4*)t;
}

// ---------------------------------------------------------------------------
// Unified bf16 NT MFMA core: BM x 128 tile, BK=32, 4 waves 2x2,
// [row][32] LDS panels (64 B rows).
// ---------------------------------------------------------------------------
template<int BM, int WM>
__device__ __forceinline__ void gemm_core(
    const unsigned short* Ap, const unsigned short* Bp,
    int K, int lda, int ldb,
    unsigned short* As, unsigned short* Bs,
    f32x4 (&acc)[WM][4])
{
    const int tid  = threadIdx.x;
    const int lane = tid & 63;
    const int w    = tid >> 6;
    const int wr   = w >> 1, wc = w & 1;
    const int l15  = lane & 15, lk = lane >> 4;

    for (int kt = 0; kt < K; kt += 32) {
        __syncthreads();
        #pragma unroll
        for (int c = 0; c < BM / 64; ++c) {
            int o = c * 4096 + tid * 16;
            int r = o >> 6, k0 = (o & 63) >> 1;
            gl_lds16(Ap + (long)r * lda + kt + k0, (char*)As + o);
        }
        #pragma unroll
        for (int c = 0; c < 2; ++c) {
            int o = c * 4096 + tid * 16;
            int r = o >> 6, k0 = (o & 63) >> 1;
            gl_lds16(Bp + (long)r * ldb + kt + k0, (char*)Bs + o);
        }
        __syncthreads();
        bf16x8 af[WM], bfr[4];
        #pragma unroll
        for (int m = 0; m < WM; ++m) {
            int arow = wr * (BM / 2) + m * 16 + l15;
            af[m] = *(const bf16x8*)((const char*)As + arow * 64 + lk * 16);
        }
        #pragma unroll
        for (int n = 0; n < 4; ++n) {
            int bcol = wc * 64 + n * 16 + l15;
            bfr[n] = *(const bf16x8*)((const char*)Bs + bcol * 64 + lk * 16);
        }
        #pragma unroll
        for (int m = 0; m < WM; ++m)
            #pragma unroll
            for (int n = 0; n < 4; ++n)
                acc[m][n] = __builtin_amdgcn_mfma_f32_16x16x32_bf16(
                    af[m], bfr[n], acc[m][n], 0, 0, 0);
    }
}

// ---------------------------------------------------------------------------
// QKV projections. z = 0:Q 1:K 2:V.  Q: *(cos+sin)*alpha*log2e (exp2 fold);
// K: *(cos+sin); V: transposed [head][d][seq].  4x4 supertile XCD swizzle.
// ---------------------------------------------------------------------------
__global__ __launch_bounds__(256)
void k_proj(const unsigned short* __restrict__ XqB, const unsigned short* __restrict__ XkB,
            const unsigned short* __restrict__ WkB, const unsigned short* __restrict__ WqB,
            const unsigned short* __restrict__ WvB,
            const float* __restrict__ cosp, const float* __restrict__ sinp,
            unsigned short* __restrict__ Qp, unsigned short* __restrict__ Kp,
            unsigned short* __restrict__ Vp)
{
    __shared__ __align__(16) unsigned short As[128 * 32];
    __shared__ __align__(16) unsigned short Bs[128 * 32];

    // supertile swizzle: 768 blocks, 48 supertiles of 4x4 blocks, 6 per XCD
    const int lin = (blockIdx.z * 16 + blockIdx.y) * 16 + blockIdx.x;
    const int xcd = lin & 7, kk = lin >> 3;
    const int s   = xcd + (kk >> 4) * 8;          // 0..47
    const int w2  = kk & 15;
    const int blk = s * 16 + w2;
    const int z   = blk >> 8;
    const int r   = blk & 255;
    const int sid = r >> 4, wi = r & 15;
    const int row0 = ((sid >> 2) * 4 + (wi >> 2)) * 128;
    const int col0 = ((sid & 3) * 4 + (wi & 3)) * 128;

    const unsigned short* Ap = (z == 0 ? XqB : XkB) + (long)row0 * HDIM;
    const unsigned short* Bp = (z == 0 ? WkB : (z == 1 ? WqB : WvB)) + (long)col0 * HDIM;

    f32x4 acc[4][4];
    #pragma unroll
    for (int m = 0; m < 4; ++m)
        #pragma unroll
        for (int n = 0; n < 4; ++n) acc[m][n] = (f32x4){0.f, 0.f, 0.f, 0.f};

    gemm_core<128, 4>(Ap, Bp, HDIM, HDIM, HDIM, As, Bs, acc);

    const int tid = threadIdx.x, lane = tid & 63, w = tid >> 6;
    const int wr = w >> 1, wc = w & 1, l15 = lane & 15, lk = lane >> 4;

    if (z < 2) {
        unsigned short* dst = (z == 0) ? Qp : Kp;
        // alpha * log2(e) folded into Q so k_attn uses raw v_exp_f32 (2^x)
        const float sc = (z == 0) ? (0.088388347648318447f * 1.4426950408889634f)
                                  : 1.0f;
        #pragma unroll
        for (int m = 0; m < 4; ++m)
            #pragma unroll
            for (int n = 0; n < 4; ++n)
                #pragma unroll
                for (int j = 0; j < 4; ++j) {
                    int grow = row0 + wr * 64 + m * 16 + lk * 4 + j;
                    int gcol = col0 + wc * 64 + n * 16 + l15;
                    int head = gcol >> 7, d = gcol & 127;
                    float cs = (cosp[(long)grow * HD + d] + sinp[(long)grow * HD + d]) * sc;
                    dst[(long)head * SQ * HD + (long)grow * HD + d] = f2bf(acc[m][n][j] * cs);
                }
    } else {
        #pragma unroll
        for (int m = 0; m < 4; ++m)
            #pragma unroll
            for (int n = 0; n < 4; ++n)
                #pragma unroll
                for (int j = 0; j < 4; ++j) {
                    int grow = row0 + wr * 64 + m * 16 + lk * 4 + j;
                    int gcol = col0 + wc * 64 + n * 16 + l15;
                    int head = gcol >> 7, d = gcol & 127;
                    Vp[(long)head * HD * SQ + (long)d * SQ + grow] = f2bf(acc[m][n][j]);
                }
    }
}

// ---------------------------------------------------------------------------
// Fused attention, no-max softmax (exp2), double-buffered, QBLK=128.
// 256 blocks (1/CU), 512 threads = 8 waves (4 row x 2 col groups).
// LDS = KV0(32K) + KV1(32K) + PQ(32K) = 96 KB.
// Per-wave frag footprint identical to QBLK=64 version; halved staging,
// barriers, and K/V L2 traffic per unit of output.
// ---------------------------------------------------------------------------
__global__ __launch_bounds__(512)
void k_attn(const unsigned short* __restrict__ Qp, const unsigned short* __restrict__ Kp,
            const unsigned short* __restrict__ Vp, float* __restrict__ attw,
            unsigned short* __restrict__ attnB)
{
    __shared__ __align__(16) unsigned short lds[49152];   // 96 KB
    unsigned short* KV0 = lds;                 // 32 KB  (K dbuf even)
    unsigned short* KV1 = lds + 16384;         // 32 KB  (K dbuf odd / V)
    unsigned short* PQ  = lds + 32768;         // 32 KB  (Q stage -> stats -> P)
    float* sred = (float*)PQ;                  // stats overlay (Q dead by then)

    // XCD-chunked swizzle: 32 consecutive work-ids per XCD = 2 heads/XCD
    const int lin = blockIdx.y * gridDim.x + blockIdx.x;   // 0..255
    const int wg  = (lin & 7) * 32 + (lin >> 3);
    const int z   = wg >> 4;               // head
    const int r0  = (wg & 15) * 128;       // Q-row block

    const unsigned short* Qh = Qp + (long)z * SQ * HD + (long)r0 * HD;
    const unsigned short* Kh = Kp + (long)z * SQ * HD;
    const unsigned short* Vh = Vp + (long)z * HD * SQ;
    float* Wout = attw + (long)z * SQ * SQ;

    const int tid = threadIdx.x, lane = tid & 63, w = tid >> 6;   // w 0..7
    const int wr = w >> 1, wc = w & 1, l15 = lane & 15, lk = lane >> 4;

    // ---- stage Q (128 rows) + K0 ----
    stage512<128>(Qh, HD, PQ);
    stage512<128>(Kh, HD, KV0);
    __syncthreads();

    bf16x8 qf[2][4];
    #pragma unroll
    for (int m = 0; m < 2; ++m)
        #pragma unroll
        for (int s = 0; s < 4; ++s)
            qf[m][s] = frag_ld(PQ, wr * 32 + m * 16 + l15, 4 * s + lk);

    float lreg[8];
    #pragma unroll
    for (int r = 0; r < 8; ++r) lreg[r] = 0.0f;

    // ================= pass 1: exp2-sums (K double-buffered) ================
    for (int t = 0; t < 16; ++t) {
        unsigned short* cur = (t & 1) ? KV1 : KV0;
        unsigned short* nxt = (t & 1) ? KV0 : KV1;
        if (t < 15) stage512<128>(Kh + (long)(t + 1) * 128 * HD, HD, nxt);
        f32x4 s_[2][4];
        #pragma unroll
        for (int m = 0; m < 2; ++m)
            #pragma unroll
            for (int n = 0; n < 4; ++n) s_[m][n] = (f32x4){0.f, 0.f, 0.f, 0.f};
        #pragma unroll
        for (int ks = 0; ks < 4; ++ks) {
            bf16x8 bf[4];
            #pragma unroll
            for (int n = 0; n < 4; ++n)
                bf[n] = frag_ld(cur, wc * 64 + n * 16 + l15, 4 * ks + lk);
            #pragma unroll
            for (int m = 0; m < 2; ++m)
                #pragma unroll
                for (int n = 0; n < 4; ++n)
                    s_[m][n] = __builtin_amdgcn_mfma_f32_16x16x32_bf16(
                        qf[m][ks], bf[n], s_[m][n], 0, 0, 0);
        }
        #pragma unroll
        for (int m = 0; m < 2; ++m)
            #pragma unroll
            for (int j = 0; j < 4; ++j)
                lreg[m * 4 + j] += EXP2(s_[m][0][j]) + EXP2(s_[m][1][j]) +
                                   EXP2(s_[m][2][j]) + EXP2(s_[m][3][j]);
        __syncthreads();   // drains prefetch vmcnt + all reads of cur
    }

    // ---- restage K0 for pass 2 (overlaps stats reduction) ----
    stage512<128>(Kh, HD, KV0);

    // ---- reduce sums: across 16-lane groups, then across wc wave-groups ----
    #pragma unroll
    for (int r = 0; r < 8; ++r)
        #pragma unroll
        for (int d = 1; d < 16; d <<= 1)
            lreg[r] += __shfl_xor(lreg[r], d, 64);
    if (l15 == 0) {
        #pragma unroll
        for (int r = 0; r < 8; ++r) {
            int lr = wr * 32 + (r >> 2) * 16 + lk * 4 + (r & 3);   // 0..127
            sred[wc * 128 + lr] = lreg[r];
        }
    }
    __syncthreads();
    if (tid < 128) sred[256 + tid] = 1.0f / (sred[tid] + sred[128 + tid]);
    __syncthreads();

    float lrow[8];
    #pragma unroll
    for (int m = 0; m < 2; ++m)
        #pragma unroll
        for (int j = 0; j < 4; ++j)
            lrow[m * 4 + j] = sred[256 + wr * 32 + m * 16 + lk * 4 + j];
    __syncthreads();   // everyone has lrow; PQ free for P reuse; K0 staged

    f32x4 pv[2][4];
    #pragma unroll
    for (int m = 0; m < 2; ++m)
        #pragma unroll
        for (int n = 0; n < 4; ++n) pv[m][n] = (f32x4){0.f, 0.f, 0.f, 0.f};

    // ================= pass 2: weights + PV (K in KV0, V in KV1) ============
    for (int t = 0; t < 16; ++t) {
        stage512<128>(Vh + (long)t * 128, SQ, KV1);   // V_t, hides under QK
        f32x4 s_[2][4];
        #pragma unroll
        for (int m = 0; m < 2; ++m)
            #pragma unroll
            for (int n = 0; n < 4; ++n) s_[m][n] = (f32x4){0.f, 0.f, 0.f, 0.f};
        #pragma unroll
        for (int ks = 0; ks < 4; ++ks) {
            bf16x8 bf[4];
            #pragma unroll
            for (int n = 0; n < 4; ++n)
                bf[n] = frag_ld(KV0, wc * 64 + n * 16 + l15, 4 * ks + lk);
            #pragma unroll
            for (int m = 0; m < 2; ++m)
                #pragma unroll
                for (int n = 0; n < 4; ++n)
                    s_[m][n] = __builtin_amdgcn_mfma_f32_16x16x32_bf16(
                        qf[m][ks], bf[n], s_[m][n], 0, 0, 0);
        }
        // P: normalize in regs, bf16 -> PQ (f32 store deferred past barrier)
        #pragma unroll
        for (int m = 0; m < 2; ++m)
            #pragma unroll
            for (int n = 0; n < 4; ++n)
                #pragma unroll
                for (int j = 0; j < 4; ++j) {
                    const int r   = m * 4 + j;
                    const int lr  = wr * 32 + m * 16 + lk * 4 + j;
                    const int col = wc * 64 + n * 16 + l15;
                    s_[m][n][j] = EXP2(s_[m][n][j]) * lrow[r];
                    p_st(PQ, lr, col, f2bf(s_[m][n][j]));
                }
        __syncthreads();   // V_t staged; K reads + P writes complete
        if (t < 15) stage512<128>(Kh + (long)(t + 1) * 128 * HD, HD, KV0);
        // deferred weight stores: drain overlaps PV
        #pragma unroll
        for (int m = 0; m < 2; ++m)
            #pragma unroll
            for (int n = 0; n < 4; ++n)
                #pragma unroll
                for (int j = 0; j < 4; ++j) {
                    const int lr  = wr * 32 + m * 16 + lk * 4 + j;
                    const int col = wc * 64 + n * 16 + l15;
                    __builtin_nontemporal_store(
                        s_[m][n][j], &Wout[(long)(r0 + lr) * SQ + t * 128 + col]);
                }
        #pragma unroll
        for (int ks = 0; ks < 4; ++ks) {
            bf16x8 pa[2], vb[4];
            #pragma unroll
            for (int m = 0; m < 2; ++m)
                pa[m] = frag_ld(PQ, wr * 32 + m * 16 + l15, 4 * ks + lk);
            #pragma unroll
            for (int n = 0; n < 4; ++n)
                vb[n] = frag_ld(KV1, wc * 64 + n * 16 + l15, 4 * ks + lk);
            #pragma unroll
            for (int m = 0; m < 2; ++m)
                #pragma unroll
                for (int n = 0; n < 4; ++n)
                    pv[m][n] = __builtin_amdgcn_mfma_f32_16x16x32_bf16(
                        pa[m], vb[n], pv[m][n], 0, 0, 0);
        }
        __syncthreads();   // K_{t+1} staged; V/P reads complete
    }

    // ---- epilogue: attn (bf16, [seq][h*128+d]) ----
    #pragma unroll
    for (int m = 0; m < 2; ++m)
        #pragma unroll
        for (int n = 0; n < 4; ++n)
            #pragma unroll
            for (int j = 0; j < 4; ++j) {
                long grow = r0 + wr * 32 + m * 16 + lk * 4 + j;
                int  gcol = wc * 64 + n * 16 + l15;
                attnB[grow * HDIM + (long)z * HD + gcol] = f2bf(pv[m][n][j]);
            }
}

// ---------------------------------------------------------------------------
// out = attn @ Wo^T.  BM=64 -> 512 blocks (2/CU).  8x4 supertile XCD swizzle.
// ---------------------------------------------------------------------------
__global__ __launch_bounds__(256)
void k_out(const unsigned short* __restrict__ attnB, const unsigned short* __restrict__ WoB,
           float* __restrict__ out)
{
    __shared__ __align__(16) unsigned short As[64 * 32];
    __shared__ __align__(16) unsigned short Bs[128 * 32];

    // 512 blocks, 16 supertiles of 8x4 blocks (A 2MB + B 2MB per supertile)
    const int lin = blockIdx.y * gridDim.x + blockIdx.x;
    const int xcd = lin & 7, kk = lin >> 3;
    const int s   = xcd + (kk >> 5) * 8;          // 0..15
    const int wi  = kk & 31;
    const int row0 = ((s >> 2) * 8 + (wi >> 2)) * 64;
    const int col0 = ((s & 3) * 4 + (wi & 3)) * 128;

    const unsigned short* Ap = attnB + (long)row0 * HDIM;
    const unsigned short* Bp = WoB + (long)col0 * HDIM;

    f32x4 acc[2][4];
    #pragma unroll
    for (int m = 0; m < 2; ++m)
        #pragma unroll
        for (int n = 0; n < 4; ++n) acc[m][n] = (f32x4){0.f, 0.f, 0.f, 0.f};

    gemm_core<64, 2>(Ap, Bp, HDIM, HDIM, HDIM, As, Bs, acc);

    const int tid = threadIdx.x, lane = tid & 63, w = tid >> 6;
    const int wr = w >> 1, wc = w & 1, l15 = lane & 15, lk = lane >> 4;
    #pragma unroll
    for (int m = 0; m < 2; ++m)
        #pragma unroll
        for (int n = 0; n < 4; ++n)
            #pragma unroll
            for (int j = 0; j < 4; ++j) {
                long grow = row0 + wr * 32 + m * 16 + lk * 4 + j;
                long gcol = col0 + wc * 64 + n * 16 + l15;
                out[grow * HDIM + gcol] = acc[m][n][j];
            }
}

// ---------------------------------------------------------------------------
extern "C" void kernel_launch(void* const* d_in, const int* in_sizes, int n_in,
                              void* d_out, int out_size, void* d_ws, size_t ws_size,
                              hipStream_t stream)
{
    const float* Xq   = (const float*)d_in[0];
    const float* Xk   = (const float*)d_in[1];
    const float* cosp = (const float*)d_in[2];
    const float* sinp = (const float*)d_in[3];
    const float* Wq   = (const float*)d_in[4];
    const float* Wk   = (const float*)d_in[5];
    const float* Wv   = (const float*)d_in[6];
    const float* Wo   = (const float*)d_in[7];

    float* out  = (float*)d_out;
    float* attw = out + (long)SQ * HDIM;            // (NH,S,S) f32 weights out

    const long TE = (long)SQ * HDIM;

    unsigned short* Qp    = (unsigned short*)d_ws;  // [head][seq][d]
    unsigned short* Kp    = Qp + TE;                // [head][seq][d]
    unsigned short* Vp    = Kp + TE;                // [head][d][seq]
    unsigned short* attnB = Vp + TE;                // [seq][h*128+d]
    unsigned short* WoB   = attnB + TE;

    // bf16 staging of X/W inside the not-yet-written attw region
    unsigned short* stg = (unsigned short*)attw;
    unsigned short* XqB = stg;
    unsigned short* XkB = stg + TE;
    unsigned short* WkB = stg + 2 * TE;
    unsigned short* WqB = stg + 3 * TE;
    unsigned short* WvB = stg + 4 * TE;

    dim3 blk(256);

    CvtPtrs cp;
    cp.s[0] = Xq; cp.d[0] = XqB;
    cp.s[1] = Xk; cp.d[1] = XkB;
    cp.s[2] = Wk; cp.d[2] = WkB;
    cp.s[3] = Wq; cp.d[3] = WqB;
    cp.s[4] = Wv; cp.d[4] = WvB;
    cp.s[5] = Wo; cp.d[5] = WoB;
    k_cvt6<<<dim3((int)(TE / (8 * 256)), 1, 6), blk, 0, stream>>>(cp, TE);

    k_proj<<<dim3(16, 16, 3), blk, 0, stream>>>(XqB, XkB, WkB, WqB, WvB,
                                                cosp, sinp, Qp, Kp, Vp);

    // fused scores + no-max softmax (exp2) + weights-write + PV, QBLK=128
    k_attn<<<dim3(16, 16), dim3(512), 0, stream>>>(Qp, Kp, Vp, attw, attnB);

    k_out<<<dim3(16, 32), blk, 0, stream>>>(attnB, WoB, out);
}

// Round 11
// 233.174 us; speedup vs baseline: 1.0881x; 1.0881x over previous
//
#include <hip/hip_runtime.h>

#define SQ   2048
#define HD   128
#define NH   16
#define HDIM 2048

typedef short bf16x8 __attribute__((ext_vector_type(8)));
typedef float f32x4  __attribute__((ext_vector_type(4)));

#if __has_builtin(__builtin_amdgcn_exp2f)
#define EXP2(x) __builtin_amdgcn_exp2f(x)
#else
#define EXP2(x) exp2f(x)
#endif

__device__ __forceinline__ unsigned short f2bf(float x) {
    union { float f; unsigned u; } v; v.f = x;
    unsigned r = v.u + 0x7fffu + ((v.u >> 16) & 1u);   // RNE
    return (unsigned short)(r >> 16);
}

__device__ __forceinline__ void gl_lds16(const void* g, void* l) {
    __builtin_amdgcn_global_load_lds(
        (const __attribute__((address_space(1))) unsigned*)g,
        (__attribute__((address_space(3))) unsigned*)l, 16, 0, 0);
}

// ---------------------------------------------------------------------------
// Swizzled tile staging: ROWS x 128 bf16, row stride 256 B, 16B-chunk index
// XORed with (row&7).  gl_lds dest is linear; swizzle applied by permuting
// the per-lane GLOBAL source (both-sides-or-neither rule).
// ---------------------------------------------------------------------------
template<int ROWS>
__device__ __forceinline__ void stage_tile(const unsigned short* __restrict__ src,
                                           long ld, unsigned short* dst)
{
    const int tid = threadIdx.x;
    #pragma unroll
    for (int c = 0; c < ROWS / 16; ++c) {
        int o   = c * 4096 + tid * 16;        // linear phys byte offset
        int row = o >> 8;
        int pch = (o >> 4) & 15;              // phys 16B chunk in row
        int lch = pch ^ (row & 7);            // logical chunk (involution)
        gl_lds16(src + (long)row * ld + lch * 8, (char*)dst + o);
    }
}

__device__ __forceinline__ bf16x8 frag_ld(const unsigned short* buf, int row, int chunk)
{
    int o = row * 256 + ((chunk ^ (row & 7)) << 4);
    return *(const bf16x8*)((const char*)buf + o);
}

__device__ __forceinline__ void p_st(unsigned short* buf, int row, int col, unsigned short v)
{
    int o = row * 256 + ((((col >> 3) ^ (row & 7))) << 4) + ((col & 7) << 1);
    *(unsigned short*)((char*)buf + o) = v;
}

// ---------------------------------------------------------------------------
// f32 -> bf16, 6 tensors in one launch (blockIdx.z selects tensor)
// ---------------------------------------------------------------------------
struct CvtPtrs {
    const float* s[6];
    unsigned short* d[6];
};

__global__ __launch_bounds__(256)
void k_cvt6(CvtPtrs p, long n)
{
    const float* __restrict__ s = p.s[blockIdx.z];
    unsigned short* __restrict__ d = p.d[blockIdx.z];
    long i = ((long)blockIdx.x * 256 + threadIdx.x) * 8;
    if (i >= n) return;
    float4 a = *(const float4*)(s + i);
    float4 b = *(const float4*)(s + i + 4);
    unsigned short t[8] = { f2bf(a.x), f2bf(a.y), f2bf(a.z), f2bf(a.w),
                            f2bf(b.x), f2bf(b.y), f2bf(b.z), f2bf(b.w) };
    *(int4*)(d + i) = *(const int4*)t;
}

// ---------------------------------------------------------------------------
// Unified bf16 NT MFMA core: BM x 128 tile, BK=32, 4 waves 2x2,
// [row][32] LDS panels (64 B rows).
// ---------------------------------------------------------------------------
template<int BM, int WM>
__device__ __forceinline__ void gemm_core(
    const unsigned short* Ap, const unsigned short* Bp,
    int K, int lda, int ldb,
    unsigned short* As, unsigned short* Bs,
    f32x4 (&acc)[WM][4])
{
    const int tid  = threadIdx.x;
    const int lane = tid & 63;
    const int w    = tid >> 6;
    const int wr   = w >> 1, wc = w & 1;
    const int l15  = lane & 15, lk = lane >> 4;

    for (int kt = 0; kt < K; kt += 32) {
        __syncthreads();
        #pragma unroll
        for (int c = 0; c < BM / 64; ++c) {
            int o = c * 4096 + tid * 16;
            int r = o >> 6, k0 = (o & 63) >> 1;
            gl_lds16(Ap + (long)r * lda + kt + k0, (char*)As + o);
        }
        #pragma unroll
        for (int c = 0; c < 2; ++c) {
            int o = c * 4096 + tid * 16;
            int r = o >> 6, k0 = (o & 63) >> 1;
            gl_lds16(Bp + (long)r * ldb + kt + k0, (char*)Bs + o);
        }
        __syncthreads();
        bf16x8 af[WM], bfr[4];
        #pragma unroll
        for (int m = 0; m < WM; ++m) {
            int arow = wr * (BM / 2) + m * 16 + l15;
            af[m] = *(const bf16x8*)((const char*)As + arow * 64 + lk * 16);
        }
        #pragma unroll
        for (int n = 0; n < 4; ++n) {
            int bcol = wc * 64 + n * 16 + l15;
            bfr[n] = *(const bf16x8*)((const char*)Bs + bcol * 64 + lk * 16);
        }
        #pragma unroll
        for (int m = 0; m < WM; ++m)
            #pragma unroll
            for (int n = 0; n < 4; ++n)
                acc[m][n] = __builtin_amdgcn_mfma_f32_16x16x32_bf16(
                    af[m], bfr[n], acc[m][n], 0, 0, 0);
    }
}

// ---------------------------------------------------------------------------
// QKV projections. z = 0:Q 1:K 2:V.  Q: *(cos+sin)*alpha*log2e (exp2 fold);
// K: *(cos+sin); V: transposed [head][d][seq].  4x4 supertile XCD swizzle.
// ---------------------------------------------------------------------------
__global__ __launch_bounds__(256)
void k_proj(const unsigned short* __restrict__ XqB, const unsigned short* __restrict__ XkB,
            const unsigned short* __restrict__ WkB, const unsigned short* __restrict__ WqB,
            const unsigned short* __restrict__ WvB,
            const float* __restrict__ cosp, const float* __restrict__ sinp,
            unsigned short* __restrict__ Qp, unsigned short* __restrict__ Kp,
            unsigned short* __restrict__ Vp)
{
    __shared__ __align__(16) unsigned short As[128 * 32];
    __shared__ __align__(16) unsigned short Bs[128 * 32];

    // supertile swizzle: 768 blocks, 48 supertiles of 4x4 blocks, 6 per XCD
    const int lin = (blockIdx.z * 16 + blockIdx.y) * 16 + blockIdx.x;
    const int xcd = lin & 7, kk = lin >> 3;
    const int s   = xcd + (kk >> 4) * 8;          // 0..47
    const int w2  = kk & 15;
    const int blk = s * 16 + w2;
    const int z   = blk >> 8;
    const int r   = blk & 255;
    const int sid = r >> 4, wi = r & 15;
    const int row0 = ((sid >> 2) * 4 + (wi >> 2)) * 128;
    const int col0 = ((sid & 3) * 4 + (wi & 3)) * 128;

    const unsigned short* Ap = (z == 0 ? XqB : XkB) + (long)row0 * HDIM;
    const unsigned short* Bp = (z == 0 ? WkB : (z == 1 ? WqB : WvB)) + (long)col0 * HDIM;

    f32x4 acc[4][4];
    #pragma unroll
    for (int m = 0; m < 4; ++m)
        #pragma unroll
        for (int n = 0; n < 4; ++n) acc[m][n] = (f32x4){0.f, 0.f, 0.f, 0.f};

    gemm_core<128, 4>(Ap, Bp, HDIM, HDIM, HDIM, As, Bs, acc);

    const int tid = threadIdx.x, lane = tid & 63, w = tid >> 6;
    const int wr = w >> 1, wc = w & 1, l15 = lane & 15, lk = lane >> 4;

    if (z < 2) {
        unsigned short* dst = (z == 0) ? Qp : Kp;
        // alpha * log2(e) folded into Q so k_attn uses raw v_exp_f32 (2^x)
        const float sc = (z == 0) ? (0.088388347648318447f * 1.4426950408889634f)
                                  : 1.0f;
        #pragma unroll
        for (int m = 0; m < 4; ++m)
            #pragma unroll
            for (int n = 0; n < 4; ++n)
                #pragma unroll
                for (int j = 0; j < 4; ++j) {
                    int grow = row0 + wr * 64 + m * 16 + lk * 4 + j;
                    int gcol = col0 + wc * 64 + n * 16 + l15;
                    int head = gcol >> 7, d = gcol & 127;
                    float cs = (cosp[(long)grow * HD + d] + sinp[(long)grow * HD + d]) * sc;
                    dst[(long)head * SQ * HD + (long)grow * HD + d] = f2bf(acc[m][n][j] * cs);
                }
    } else {
        #pragma unroll
        for (int m = 0; m < 4; ++m)
            #pragma unroll
            for (int n = 0; n < 4; ++n)
                #pragma unroll
                for (int j = 0; j < 4; ++j) {
                    int grow = row0 + wr * 64 + m * 16 + lk * 4 + j;
                    int gcol = col0 + wc * 64 + n * 16 + l15;
                    int head = gcol >> 7, d = gcol & 127;
                    Vp[(long)head * HD * SQ + (long)d * SQ + grow] = f2bf(acc[m][n][j]);
                }
    }
}

// ---------------------------------------------------------------------------
// Fused attention, no-max softmax (exp2 form), double-buffered.
// LDS = KV0(32K) + KV1(32K) + PQ(16K) = exactly 80 KB -> 2 blocks/CU.
// Round-6 schedule: no setprio, weight stores direct from regs after the
// mid-barrier (drain overlaps PV).
// ---------------------------------------------------------------------------
__global__ __launch_bounds__(256)
void k_attn(const unsigned short* __restrict__ Qp, const unsigned short* __restrict__ Kp,
            const unsigned short* __restrict__ Vp, float* __restrict__ attw,
            unsigned short* __restrict__ attnB)
{
    __shared__ __align__(16) unsigned short lds[40960];   // 80 KB exactly
    unsigned short* KV0 = lds;                 // 32 KB  (K buffer / dbuf even)
    unsigned short* KV1 = lds + 16384;         // 32 KB  (V buffer / dbuf odd)
    unsigned short* PQ  = lds + 32768;         // 16 KB  (Q stage -> stats -> P)
    float* sred = (float*)PQ;                  // stats overlay (Q dead by then)

    // XCD-chunked swizzle: 64 consecutive work-ids per XCD = 2 heads/XCD
    const int lin = blockIdx.y * gridDim.x + blockIdx.x;
    const int wg  = (lin & 7) * 64 + (lin >> 3);
    const int z   = wg >> 5;               // head
    const int r0  = (wg & 31) * 64;        // Q-row block

    const unsigned short* Qh = Qp + (long)z * SQ * HD + (long)r0 * HD;
    const unsigned short* Kh = Kp + (long)z * SQ * HD;
    const unsigned short* Vh = Vp + (long)z * HD * SQ;
    float* Wout = attw + (long)z * SQ * SQ;

    const int tid = threadIdx.x, lane = tid & 63, w = tid >> 6;
    const int wr = w >> 1, wc = w & 1, l15 = lane & 15, lk = lane >> 4;

    // ---- stage Q + K0 ----
    stage_tile<64>(Qh, HD, PQ);
    stage_tile<128>(Kh, HD, KV0);
    __syncthreads();

    bf16x8 qf[2][4];
    #pragma unroll
    for (int m = 0; m < 2; ++m)
        #pragma unroll
        for (int s = 0; s < 4; ++s)
            qf[m][s] = frag_ld(PQ, wr * 32 + m * 16 + l15, 4 * s + lk);

    float lreg[8];
    #pragma unroll
    for (int r = 0; r < 8; ++r) lreg[r] = 0.0f;

    // ================= pass 1: exp2-sums (K double-buffered) ================
    for (int t = 0; t < 16; ++t) {
        unsigned short* cur = (t & 1) ? KV1 : KV0;
        unsigned short* nxt = (t & 1) ? KV0 : KV1;
        if (t < 15) stage_tile<128>(Kh + (long)(t + 1) * 128 * HD, HD, nxt);
        f32x4 s_[2][4];
        #pragma unroll
        for (int m = 0; m < 2; ++m)
            #pragma unroll
            for (int n = 0; n < 4; ++n) s_[m][n] = (f32x4){0.f, 0.f, 0.f, 0.f};
        #pragma unroll
        for (int ks = 0; ks < 4; ++ks) {
            bf16x8 bf[4];
            #pragma unroll
            for (int n = 0; n < 4; ++n)
                bf[n] = frag_ld(cur, wc * 64 + n * 16 + l15, 4 * ks + lk);
            #pragma unroll
            for (int m = 0; m < 2; ++m)
                #pragma unroll
                for (int n = 0; n < 4; ++n)
                    s_[m][n] = __builtin_amdgcn_mfma_f32_16x16x32_bf16(
                        qf[m][ks], bf[n], s_[m][n], 0, 0, 0);
        }
        #pragma unroll
        for (int m = 0; m < 2; ++m)
            #pragma unroll
            for (int j = 0; j < 4; ++j)
                lreg[m * 4 + j] += EXP2(s_[m][0][j]) + EXP2(s_[m][1][j]) +
                                   EXP2(s_[m][2][j]) + EXP2(s_[m][3][j]);
        __syncthreads();   // drains prefetch vmcnt + all reads of cur
    }

    // ---- restage K0 for pass 2 (overlaps stats reduction) ----
    stage_tile<128>(Kh, HD, KV0);

    // ---- reduce sums: across 16-lane groups, then across wc waves ----
    #pragma unroll
    for (int r = 0; r < 8; ++r)
        #pragma unroll
        for (int d = 1; d < 16; d <<= 1)
            lreg[r] += __shfl_xor(lreg[r], d, 64);
    if (l15 == 0) {
        #pragma unroll
        for (int r = 0; r < 8; ++r) {
            int lr = wr * 32 + (r >> 2) * 16 + lk * 4 + (r & 3);
            sred[wc * 64 + lr] = lreg[r];
        }
    }
    __syncthreads();
    if (tid < 64) sred[128 + tid] = 1.0f / (sred[tid] + sred[64 + tid]);
    __syncthreads();

    float lrow[8];
    #pragma unroll
    for (int m = 0; m < 2; ++m)
        #pragma unroll
        for (int j = 0; j < 4; ++j)
            lrow[m * 4 + j] = sred[128 + wr * 32 + m * 16 + lk * 4 + j];
    __syncthreads();   // everyone has lrow; PQ free for P reuse; K0 staged

    f32x4 pv[2][4];
    #pragma unroll
    for (int m = 0; m < 2; ++m)
        #pragma unroll
        for (int n = 0; n < 4; ++n) pv[m][n] = (f32x4){0.f, 0.f, 0.f, 0.f};

    // ================= pass 2: weights + PV (K in KV0, V in KV1) ============
    for (int t = 0; t < 16; ++t) {
        stage_tile<128>(Vh + (long)t * 128, SQ, KV1);   // V_t, hides under QK
        f32x4 s_[2][4];
        #pragma unroll
        for (int m = 0; m < 2; ++m)
            #pragma unroll
            for (int n = 0; n < 4; ++n) s_[m][n] = (f32x4){0.f, 0.f, 0.f, 0.f};
        #pragma unroll
        for (int ks = 0; ks < 4; ++ks) {
            bf16x8 bf[4];
            #pragma unroll
            for (int n = 0; n < 4; ++n)
                bf[n] = frag_ld(KV0, wc * 64 + n * 16 + l15, 4 * ks + lk);
            #pragma unroll
            for (int m = 0; m < 2; ++m)
                #pragma unroll
                for (int n = 0; n < 4; ++n)
                    s_[m][n] = __builtin_amdgcn_mfma_f32_16x16x32_bf16(
                        qf[m][ks], bf[n], s_[m][n], 0, 0, 0);
        }
        // P: normalize in regs, bf16 -> PQ (f32 store deferred past barrier)
        #pragma unroll
        for (int m = 0; m < 2; ++m)
            #pragma unroll
            for (int n = 0; n < 4; ++n)
                #pragma unroll
                for (int j = 0; j < 4; ++j) {
                    const int r   = m * 4 + j;
                    const int lr  = wr * 32 + m * 16 + lk * 4 + j;
                    const int col = wc * 64 + n * 16 + l15;
                    s_[m][n][j] = EXP2(s_[m][n][j]) * lrow[r];
                    p_st(PQ, lr, col, f2bf(s_[m][n][j]));
                }
        __syncthreads();   // V_t staged; K reads + P writes complete
        if (t < 15) stage_tile<128>(Kh + (long)(t + 1) * 128 * HD, HD, KV0);
        // deferred weight stores: drain overlaps PV
        #pragma unroll
        for (int m = 0; m < 2; ++m)
            #pragma unroll
            for (int n = 0; n < 4; ++n)
                #pragma unroll
                for (int j = 0; j < 4; ++j) {
                    const int lr  = wr * 32 + m * 16 + lk * 4 + j;
                    const int col = wc * 64 + n * 16 + l15;
                    __builtin_nontemporal_store(
                        s_[m][n][j], &Wout[(long)(r0 + lr) * SQ + t * 128 + col]);
                }
        #pragma unroll
        for (int ks = 0; ks < 4; ++ks) {
            bf16x8 pa[2], vb[4];
            #pragma unroll
            for (int m = 0; m < 2; ++m)
                pa[m] = frag_ld(PQ, wr * 32 + m * 16 + l15, 4 * ks + lk);
            #pragma unroll
            for (int n = 0; n < 4; ++n)
                vb[n] = frag_ld(KV1, wc * 64 + n * 16 + l15, 4 * ks + lk);
            #pragma unroll
            for (int m = 0; m < 2; ++m)
                #pragma unroll
                for (int n = 0; n < 4; ++n)
                    pv[m][n] = __builtin_amdgcn_mfma_f32_16x16x32_bf16(
                        pa[m], vb[n], pv[m][n], 0, 0, 0);
        }
        __syncthreads();   // K_{t+1} staged; V/P reads complete
    }

    // ---- epilogue: attn (bf16, [seq][h*128+d]) ----
    #pragma unroll
    for (int m = 0; m < 2; ++m)
        #pragma unroll
        for (int n = 0; n < 4; ++n)
            #pragma unroll
            for (int j = 0; j < 4; ++j) {
                long grow = r0 + wr * 32 + m * 16 + lk * 4 + j;
                int  gcol = wc * 64 + n * 16 + l15;
                attnB[grow * HDIM + (long)z * HD + gcol] = f2bf(pv[m][n][j]);
            }
}

// ---------------------------------------------------------------------------
// out = attn @ Wo^T.  BM=64 -> 512 blocks (2/CU).  8x4 supertile XCD swizzle.
// ---------------------------------------------------------------------------
__global__ __launch_bounds__(256)
void k_out(const unsigned short* __restrict__ attnB, const unsigned short* __restrict__ WoB,
           float* __restrict__ out)
{
    __shared__ __align__(16) unsigned short As[64 * 32];
    __shared__ __align__(16) unsigned short Bs[128 * 32];

    // 512 blocks, 16 supertiles of 8x4 blocks (A 2MB + B 2MB per supertile)
    const int lin = blockIdx.y * gridDim.x + blockIdx.x;
    const int xcd = lin & 7, kk = lin >> 3;
    const int s   = xcd + (kk >> 5) * 8;          // 0..15
    const int wi  = kk & 31;
    const int row0 = ((s >> 2) * 8 + (wi >> 2)) * 64;
    const int col0 = ((s & 3) * 4 + (wi & 3)) * 128;

    const unsigned short* Ap = attnB + (long)row0 * HDIM;
    const unsigned short* Bp = WoB + (long)col0 * HDIM;

    f32x4 acc[2][4];
    #pragma unroll
    for (int m = 0; m < 2; ++m)
        #pragma unroll
        for (int n = 0; n < 4; ++n) acc[m][n] = (f32x4){0.f, 0.f, 0.f, 0.f};

    gemm_core<64, 2>(Ap, Bp, HDIM, HDIM, HDIM, As, Bs, acc);

    const int tid = threadIdx.x, lane = tid & 63, w = tid >> 6;
    const int wr = w >> 1, wc = w & 1, l15 = lane & 15, lk = lane >> 4;
    #pragma unroll
    for (int m = 0; m < 2; ++m)
        #pragma unroll
        for (int n = 0; n < 4; ++n)
            #pragma unroll
            for (int j = 0; j < 4; ++j) {
                long grow = row0 + wr * 32 + m * 16 + lk * 4 + j;
                long gcol = col0 + wc * 64 + n * 16 + l15;
                out[grow * HDIM + gcol] = acc[m][n][j];
            }
}

// ---------------------------------------------------------------------------
extern "C" void kernel_launch(void* const* d_in, const int* in_sizes, int n_in,
                              void* d_out, int out_size, void* d_ws, size_t ws_size,
                              hipStream_t stream)
{
    const float* Xq   = (const float*)d_in[0];
    const float* Xk   = (const float*)d_in[1];
    const float* cosp = (const float*)d_in[2];
    const float* sinp = (const float*)d_in[3];
    const float* Wq   = (const float*)d_in[4];
    const float* Wk   = (const float*)d_in[5];
    const float* Wv   = (const float*)d_in[6];
    const float* Wo   = (const float*)d_in[7];

    float* out  = (float*)d_out;
    float* attw = out + (long)SQ * HDIM;            // (NH,S,S) f32 weights out

    const long TE = (long)SQ * HDIM;

    unsigned short* Qp    = (unsigned short*)d_ws;  // [head][seq][d]
    unsigned short* Kp    = Qp + TE;                // [head][seq][d]
    unsigned short* Vp    = Kp + TE;                // [head][d][seq]
    unsigned short* attnB = Vp + TE;                // [seq][h*128+d]
    unsigned short* WoB   = attnB + TE;

    // bf16 staging of X/W inside the not-yet-written attw region
    unsigned short* stg = (unsigned short*)attw;
    unsigned short* XqB = stg;
    unsigned short* XkB = stg + TE;
    unsigned short* WkB = stg + 2 * TE;
    unsigned short* WqB = stg + 3 * TE;
    unsigned short* WvB = stg + 4 * TE;

    dim3 blk(256);

    CvtPtrs cp;
    cp.s[0] = Xq; cp.d[0] = XqB;
    cp.s[1] = Xk; cp.d[1] = XkB;
    cp.s[2] = Wk; cp.d[2] = WkB;
    cp.s[3] = Wq; cp.d[3] = WqB;
    cp.s[4] = Wv; cp.d[4] = WvB;
    cp.s[5] = Wo; cp.d[5] = WoB;
    k_cvt6<<<dim3((int)(TE / (8 * 256)), 1, 6), blk, 0, stream>>>(cp, TE);

    k_proj<<<dim3(16, 16, 3), blk, 0, stream>>>(XqB, XkB, WkB, WqB, WvB,
                                                cosp, sinp, Qp, Kp, Vp);

    // fused scores + no-max softmax (exp2) + weights-write + PV
    k_attn<<<dim3(32, 16), blk, 0, stream>>>(Qp, Kp, Vp, attw, attnB);

    k_out<<<dim3(16, 32), blk, 0, stream>>>(attnB, WoB, out);
}